// Round 4
// baseline (134.849 us; speedup 1.0000x reference)
//
#include <hip/hip_runtime.h>

#define L 1024
#define C 16
#define RT 64            // rows of M per block
#define JT 32            // K-tile (= one MFMA K)
#define ASTR 40          // bf16/row for M tile: 80 B stride -> 2-way banks (free)
#define XSTR 40          // bf16/row for transposed x tile

typedef __attribute__((ext_vector_type(8))) short short8v;  // bf16x8 A/B frag
typedef __attribute__((ext_vector_type(4))) float f32x4;    // fp32 C/D frag

// fp32 -> bf16 round-to-nearest-even (inputs are finite; no NaN path needed)
static __device__ __forceinline__ short f2bf(float f) {
  unsigned u = __builtin_bit_cast(unsigned, f);
  u = (u + 0x7fffu + ((u >> 16) & 1u)) >> 16;
  return (short)u;
}

// lgkmcnt(0) + raw s_barrier: do NOT drain vmcnt — in-flight global prefetch
// lives in wave-private VGPRs. __syncthreads() would drain vmcnt(0) and kill
// the cross-barrier pipeline.
__device__ __forceinline__ void block_sync_lds() {
  asm volatile("s_waitcnt lgkmcnt(0)" ::: "memory");
  __builtin_amdgcn_s_barrier();
}

__global__ void starts_kernel(const int* __restrict__ batch, int n, int bp1,
                              int* __restrict__ starts) {
  int i = blockIdx.x * blockDim.x + threadIdx.x;
  if (i >= bp1) return;
  int lo = 0, hi = n;
  while (lo < hi) { int mid = (lo + hi) >> 1; if (batch[mid] < i) lo = mid + 1; else hi = mid; }
  starts[i] = lo;
}

__global__ __launch_bounds__(256) void mp_kernel(
    const float* __restrict__ x,
    const float* __restrict__ M,
    const int*   __restrict__ starts,
    float*       __restrict__ out)
{
  __shared__ short Mt[2][RT * ASTR];   // 10.0 KB: M tile, bf16 row-major
  __shared__ short Xt[2][C * XSTR];    //  2.5 KB: x tile TRANSPOSED [ch][k]

  const int b  = blockIdx.y;
  const int sb = starts[b];
  int cnt = starts[b + 1] - sb;
  if (cnt > L) cnt = L;
  const int r0 = blockIdx.x * RT;
  if (r0 >= cnt) return;               // uniform per block

  const float* Mb = M + (size_t)b * (L * L);
  const float* xb = x + (size_t)sb * C;
  const int t = threadIdx.x;

  // staging roles: M 64x32 = 2048 elts -> 8/thread; x 32x16 = 512 -> 2/thread
  const int srow = t >> 2;             // 0..63
  const int skc  = (t & 3) << 3;       // k-chunk 0,8,16,24
  const int xj   = t >> 3;             // 0..31 (k index)
  const int xc   = (t & 7) << 1;       // channel pair 0,2,..,14

  // MFMA roles: wave wv owns output rows wv*16..+15
  const int lane = t & 63;
  const int wv   = t >> 6;             // 0..3
  const int arow = (wv << 4) + (lane & 15);
  const int kc8  = (lane >> 4) << 3;   // per-lane k chunk 0,8,16,24
  const int bcol = lane & 15;

  const int njt = (cnt + JT - 1) / JT;

  float4 mra, mrb;
  float2 xr;
  const float4 fz4 = make_float4(0.f, 0.f, 0.f, 0.f);

  auto issue = [&](int jt) {
    const int j0 = jt * JT;
    const int gr = r0 + srow;
    if (gr < cnt) {                    // row-guard: skip HBM fetch past cnt
      mra = *reinterpret_cast<const float4*>(Mb + (size_t)gr * L + j0 + skc);
      mrb = *reinterpret_cast<const float4*>(Mb + (size_t)gr * L + j0 + skc + 4);
    } else { mra = fz4; mrb = fz4; }
    // x zero past cnt: dead M columns (garbage beyond cnt) contribute 0
    xr = (j0 + xj < cnt) ? *reinterpret_cast<const float2*>(xb + (size_t)(j0 + xj) * C + xc)
                         : make_float2(0.f, 0.f);
  };
  auto write_lds = [&](int buf) {      // compiler inserts counted vmcnt here
    short8v v;
    v[0] = f2bf(mra.x); v[1] = f2bf(mra.y); v[2] = f2bf(mra.z); v[3] = f2bf(mra.w);
    v[4] = f2bf(mrb.x); v[5] = f2bf(mrb.y); v[6] = f2bf(mrb.z); v[7] = f2bf(mrb.w);
    *reinterpret_cast<short8v*>(&Mt[buf][srow * ASTR + skc]) = v;
    Xt[buf][(xc    ) * XSTR + xj] = f2bf(xr.x);   // transpose scatter (2B writes)
    Xt[buf][(xc + 1) * XSTR + xj] = f2bf(xr.y);
  };

  f32x4 acc = {0.f, 0.f, 0.f, 0.f};

  // prologue: tile 0 staged (one vmcnt stall), tile 1 left in flight
  issue(0);
  write_lds(0);
  if (njt > 1) issue(1);
  block_sync_lds();

  for (int jt = 0; jt < njt; ++jt) {
    const int cur = jt & 1;
    if (jt + 1 < njt) {
      write_lds(1 - cur);              // tile jt+1 (loads landed during prev compute)
      if (jt + 2 < njt) issue(jt + 2); // stays in flight across barrier
    }
    // A frag: M[arow][kc8..+7] contiguous b128; B frag: Xt[bcol][kc8..+7] b128
    short8v af = *reinterpret_cast<const short8v*>(&Mt[cur][arow * ASTR + kc8]);
    short8v bf = *reinterpret_cast<const short8v*>(&Xt[cur][bcol * XSTR + kc8]);
    acc = __builtin_amdgcn_mfma_f32_16x16x32_bf16(af, bf, acc, 0, 0, 0);
    block_sync_lds();
  }

  // D frag: col = lane&15, row = (lane>>4)*4 + reg  [m89-verified layout]
  const int orow = r0 + (wv << 4) + ((lane >> 4) << 2);
  #pragma unroll
  for (int r = 0; r < 4; ++r) {
    const int gr = orow + r;
    if (gr < cnt)
      out[(size_t)(sb + gr) * C + bcol] = acc[r];
  }
}

extern "C" void kernel_launch(void* const* d_in, const int* in_sizes, int n_in,
                              void* d_out, int out_size, void* d_ws, size_t ws_size,
                              hipStream_t stream) {
  const float* x     = (const float*)d_in[0];
  const float* M     = (const float*)d_in[1];
  const int*   batch = (const int*)d_in[2];
  float*       out   = (float*)d_out;
  const int n_nodes  = in_sizes[2];            // N = 65536
  const int B        = in_sizes[1] / (L * L);  // 128
  int* starts = (int*)d_ws;                    // B+1 ints of scratch

  starts_kernel<<<1, 256, 0, stream>>>(batch, n_nodes, B + 1, starts);
  dim3 grid(L / RT, B);
  mp_kernel<<<grid, dim3(256), 0, stream>>>(x, M, starts, out);
}

// Round 5
// 51.108 us; speedup vs baseline: 2.6385x; 2.6385x over previous
//
#include <hip/hip_runtime.h>

#define L 1024
#define C 16
#define RT 64            // output rows per block (4 waves x one 16x16 tile)
#define KT 32            // K per MFMA step
#define XSTR 1032        // shorts per Xt row: 2064 B stride -> 2-way banks (free)

typedef __attribute__((ext_vector_type(8))) short short8v;  // bf16x8 frag
typedef __attribute__((ext_vector_type(4))) float f32x4;    // fp32 acc frag

// fp32 -> bf16 round-to-nearest-even (finite inputs)
static __device__ __forceinline__ short f2bf(float f) {
  unsigned u = __builtin_bit_cast(unsigned, f);
  u = (u + 0x7fffu + ((u >> 16) & 1u)) >> 16;
  return (short)u;
}

__global__ void starts_kernel(const int* __restrict__ batch, int n, int bp1,
                              int* __restrict__ starts) {
  int i = blockIdx.x * blockDim.x + threadIdx.x;
  if (i >= bp1) return;
  int lo = 0, hi = n;
  while (lo < hi) { int mid = (lo + hi) >> 1; if (batch[mid] < i) lo = mid + 1; else hi = mid; }
  starts[i] = lo;
}

__global__ __launch_bounds__(256) void mp_kernel(
    const float* __restrict__ x,
    const float* __restrict__ M,
    const int*   __restrict__ starts,
    float*       __restrict__ out)
{
  // Whole-graph x, transposed [ch][k], bf16: 33 KB. Staged ONCE -> one barrier,
  // then the main loop is barrier-free (M has zero reuse; it streams from HBM
  // straight into A-fragments).
  __shared__ short Xt[C * XSTR];

  const int b  = blockIdx.y;
  const int sb = starts[b];
  int cnt = starts[b + 1] - sb;
  if (cnt > L) cnt = L;
  const int r0 = blockIdx.x * RT;
  if (r0 >= cnt) return;                 // uniform

  const int njt  = (cnt + KT - 1) / KT;
  const int jmax = njt * KT;             // <= 1024

  // ---- stage x transposed, zero-filled to jmax (dead M cols contribute 0) ----
  const float* xb = x + (size_t)sb * C;
  const int t = threadIdx.x;
  for (int j0 = t * 2; j0 < jmax; j0 += 512) {   // 2 nodes per thread-iter
    float4 va0, va1, vb0, vb1;
    const float4 fz = make_float4(0.f, 0.f, 0.f, 0.f);
    if (j0 < cnt) {
      va0 = *reinterpret_cast<const float4*>(xb + (size_t)j0 * C);
      va1 = *reinterpret_cast<const float4*>(xb + (size_t)j0 * C + 4);
      vb0 = *reinterpret_cast<const float4*>(xb + (size_t)j0 * C + 8);
      vb1 = *reinterpret_cast<const float4*>(xb + (size_t)j0 * C + 12);
    } else { va0 = fz; va1 = fz; vb0 = fz; vb1 = fz; }
    float4 wa0, wa1, wb0, wb1;
    if (j0 + 1 < cnt) {
      wa0 = *reinterpret_cast<const float4*>(xb + (size_t)(j0 + 1) * C);
      wa1 = *reinterpret_cast<const float4*>(xb + (size_t)(j0 + 1) * C + 4);
      wb0 = *reinterpret_cast<const float4*>(xb + (size_t)(j0 + 1) * C + 8);
      wb1 = *reinterpret_cast<const float4*>(xb + (size_t)(j0 + 1) * C + 12);
    } else { wa0 = fz; wa1 = fz; wb0 = fz; wb1 = fz; }
    const float av[16] = {va0.x,va0.y,va0.z,va0.w, va1.x,va1.y,va1.z,va1.w,
                          vb0.x,vb0.y,vb0.z,vb0.w, vb1.x,vb1.y,vb1.z,vb1.w};
    const float bv[16] = {wa0.x,wa0.y,wa0.z,wa0.w, wa1.x,wa1.y,wa1.z,wa1.w,
                          wb0.x,wb0.y,wb0.z,wb0.w, wb1.x,wb1.y,wb1.z,wb1.w};
    #pragma unroll
    for (int c = 0; c < C; ++c) {        // short2 write: (Xt[c][j0], Xt[c][j0+1])
      short2 p; p.x = f2bf(av[c]); p.y = f2bf(bv[c]);
      *reinterpret_cast<short2*>(&Xt[c * XSTR + j0]) = p;
    }
  }
  // LDS writes drained; global x-loads completed before their dependent writes.
  asm volatile("s_waitcnt lgkmcnt(0)" ::: "memory");
  __builtin_amdgcn_s_barrier();

  // ---- MFMA roles ----
  const int lane = t & 63;
  const int wv   = t >> 6;                       // wave owns rows r0+wv*16..+15
  const int arow = r0 + (wv << 4) + (lane & 15); // < 1024 always: loads never fault
  const int kc8  = (lane >> 4) << 3;             // per-lane k chunk 0,8,16,24
  const int bcol = lane & 15;
  const float* Mrow = M + (size_t)b * (L * L) + (size_t)arow * L + kc8;
  const short* Xrow = &Xt[bcol * XSTR + kc8];

  f32x4 acc = {0.f, 0.f, 0.f, 0.f};

  auto ldA = [&](int ks, float4& ra, float4& rb) {
    const float* p = Mrow + ks * KT;
    ra = *reinterpret_cast<const float4*>(p);
    rb = *reinterpret_cast<const float4*>(p + 4);
  };
  auto mk = [&](const float4& a, const float4& bq) {
    short8v v;
    v[0] = f2bf(a.x);  v[1] = f2bf(a.y);  v[2] = f2bf(a.z);  v[3] = f2bf(a.w);
    v[4] = f2bf(bq.x); v[5] = f2bf(bq.y); v[6] = f2bf(bq.z); v[7] = f2bf(bq.w);
    return v;
  };
  auto ldB = [&](int ks) {
    return *reinterpret_cast<const short8v*>(Xrow + ks * KT);
  };

  // 3-deep software pipeline, static register names (no runtime indexing).
  // Issue-to-consume distance ~3 k-steps; no barriers, waves slip freely.
  float4 A0, B0, A1, B1, A2, B2;
  ldA(0, A0, B0);
  if (njt > 1) ldA(1, A1, B1);
  if (njt > 2) ldA(2, A2, B2);

  for (int ks = 0; ks < njt; ks += 3) {
    {
      short8v bf = ldB(ks);
      acc = __builtin_amdgcn_mfma_f32_16x16x32_bf16(mk(A0, B0), bf, acc, 0, 0, 0);
      if (ks + 3 < njt) ldA(ks + 3, A0, B0);
    }
    if (ks + 1 < njt) {
      short8v bf = ldB(ks + 1);
      acc = __builtin_amdgcn_mfma_f32_16x16x32_bf16(mk(A1, B1), bf, acc, 0, 0, 0);
      if (ks + 4 < njt) ldA(ks + 4, A1, B1);
    }
    if (ks + 2 < njt) {
      short8v bf = ldB(ks + 2);
      acc = __builtin_amdgcn_mfma_f32_16x16x32_bf16(mk(A2, B2), bf, acc, 0, 0, 0);
      if (ks + 5 < njt) ldA(ks + 5, A2, B2);
    }
  }

  // D frag: col = lane&15, row = (lane>>4)*4 + reg  [validated by round 4 pass]
  const int orow = r0 + (wv << 4) + ((lane >> 4) << 2);
  #pragma unroll
  for (int r = 0; r < 4; ++r) {
    const int gr = orow + r;
    if (gr < cnt)
      out[(size_t)(sb + gr) * C + bcol] = acc[r];  // 4 rows x 64B: coalesced
  }
}

extern "C" void kernel_launch(void* const* d_in, const int* in_sizes, int n_in,
                              void* d_out, int out_size, void* d_ws, size_t ws_size,
                              hipStream_t stream) {
  const float* x     = (const float*)d_in[0];
  const float* M     = (const float*)d_in[1];
  const int*   batch = (const int*)d_in[2];
  float*       out   = (float*)d_out;
  const int n_nodes  = in_sizes[2];            // N = 65536
  const int B        = in_sizes[1] / (L * L);  // 128
  int* starts = (int*)d_ws;                    // B+1 ints of scratch

  starts_kernel<<<1, 256, 0, stream>>>(batch, n_nodes, B + 1, starts);
  dim3 grid(L / RT, B);
  mp_kernel<<<grid, dim3(256), 0, stream>>>(x, M, starts, out);
}

// Round 6
// 49.262 us; speedup vs baseline: 2.7374x; 1.0375x over previous
//
#include <hip/hip_runtime.h>
#include <hip/hip_bf16.h>

#define L 1024
#define C 16
#define RT 64            // output rows per block (4 waves x one 16x16 tile)
#define KT 32            // K per MFMA step
#define XSTR 1032        // shorts per Xt row: 2064 B stride -> balanced banks
#define DEPTH 8          // software-pipeline depth (branch-free)

typedef __attribute__((ext_vector_type(8))) short short8v;  // bf16x8 frag
typedef __attribute__((ext_vector_type(4))) float f32x4;    // fp32 acc frag

// proper bf16 convert: compiler emits v_cvt_pk_bf16_f32 for adjacent pairs
static __device__ __forceinline__ short f2bf(float f) {
  __hip_bfloat16 h = __float2bfloat16(f);
  return __builtin_bit_cast(short, h);
}
static __device__ __forceinline__ int imin(int a, int b) { return a < b ? a : b; }

// Parallel boundary scan over sorted batch: starts[g] = first i with batch[i] >= g.
__global__ void starts_kernel(const int* __restrict__ batch, int n, int nb,
                              int* __restrict__ starts) {
  int i = blockIdx.x * blockDim.x + threadIdx.x;
  if (i >= n) return;
  int cur  = batch[i];
  int prev = (i == 0) ? -1 : batch[i - 1];
  for (int g = prev + 1; g <= cur; ++g) starts[g] = i;   // usually 0-1 iters
  if (i == n - 1)
    for (int g = cur + 1; g <= nb; ++g) starts[g] = n;
}

__global__ __launch_bounds__(256, 4) void mp_kernel(
    const float* __restrict__ x,
    const float* __restrict__ M,
    const int*   __restrict__ starts,
    float*       __restrict__ out)
{
  __shared__ short Xt[C * XSTR];   // whole-graph x, transposed [ch][k], 33 KB

  // XCD swizzle: all blocks of graph b get gid === b (mod 8) -> one XCD,
  // so x/starts are fetched into that XCD's L2 once. (Heuristic: perf only.)
  const int gid = blockIdx.x;                      // 0..2047
  const int bx  = (gid >> 3) & 15;                 // row-tile 0..15
  const int b   = (gid & 7) | ((gid >> 7) << 3);   // graph 0..127 (bijective)

  const int sb = starts[b];
  int cnt = starts[b + 1] - sb;
  if (cnt > L) cnt = L;
  const int r0 = bx * RT;
  if (r0 >= cnt) return;                           // uniform

  const int njt   = (cnt + KT - 1) / KT;           // 1..32
  const int njtm1 = njt - 1;
  const int njt3  = ((njt + DEPTH - 1) / DEPTH) * DEPTH;  // <= 32
  const int jmax3 = njt3 * KT;                     // <= 1024: fake steps read zeros

  // ---- stage x transposed + bf16, zero-filled to jmax3 ----
  const float* xb = x + (size_t)sb * C;
  const int t = threadIdx.x;
  for (int j0 = t * 2; j0 < jmax3; j0 += 512) {    // 2 nodes per thread-iter
    const float4 fz = make_float4(0.f, 0.f, 0.f, 0.f);
    float4 va0 = fz, va1 = fz, vb0 = fz, vb1 = fz;
    float4 wa0 = fz, wa1 = fz, wb0 = fz, wb1 = fz;
    if (j0 < cnt) {
      va0 = *reinterpret_cast<const float4*>(xb + (size_t)j0 * C);
      va1 = *reinterpret_cast<const float4*>(xb + (size_t)j0 * C + 4);
      vb0 = *reinterpret_cast<const float4*>(xb + (size_t)j0 * C + 8);
      vb1 = *reinterpret_cast<const float4*>(xb + (size_t)j0 * C + 12);
    }
    if (j0 + 1 < cnt) {
      wa0 = *reinterpret_cast<const float4*>(xb + (size_t)(j0 + 1) * C);
      wa1 = *reinterpret_cast<const float4*>(xb + (size_t)(j0 + 1) * C + 4);
      wb0 = *reinterpret_cast<const float4*>(xb + (size_t)(j0 + 1) * C + 8);
      wb1 = *reinterpret_cast<const float4*>(xb + (size_t)(j0 + 1) * C + 12);
    }
    const float av[16] = {va0.x,va0.y,va0.z,va0.w, va1.x,va1.y,va1.z,va1.w,
                          vb0.x,vb0.y,vb0.z,vb0.w, vb1.x,vb1.y,vb1.z,vb1.w};
    const float bv[16] = {wa0.x,wa0.y,wa0.z,wa0.w, wa1.x,wa1.y,wa1.z,wa1.w,
                          wb0.x,wb0.y,wb0.z,wb0.w, wb1.x,wb1.y,wb1.z,wb1.w};
    #pragma unroll
    for (int c = 0; c < C; ++c) {                  // pairs -> v_cvt_pk_bf16_f32
      short2 p; p.x = f2bf(av[c]); p.y = f2bf(bv[c]);
      *reinterpret_cast<short2*>(&Xt[c * XSTR + j0]) = p;
    }
  }
  // Only LDS writes need draining; keep global prefetch free to fly later.
  asm volatile("s_waitcnt lgkmcnt(0)" ::: "memory");
  __builtin_amdgcn_s_barrier();

  // ---- MFMA roles: wave wv owns rows r0+wv*16..+15 ----
  const int lane = t & 63;
  const int wv   = t >> 6;
  const int arow = r0 + (wv << 4) + (lane & 15);   // < 1024: loads never fault
  const int kc8  = (lane >> 4) << 3;               // per-lane k chunk 0,8,16,24
  const int bcol = lane & 15;
  const float* Mrow = M + (size_t)b * (L * L) + (size_t)arow * L + kc8;
  const short* Xrow = &Xt[bcol * XSTR + kc8];

  f32x4 acc = {0.f, 0.f, 0.f, 0.f};

  // 8-deep branch-free pipeline. A-prefetch col clamped to njt-1 (dup reads
  // merge in L1/MSHR; their MFMA contribution is 0 since B there is zero).
#define LDA(s, ks) do { \
    const float* p_ = Mrow + (size_t)imin((ks), njtm1) * KT; \
    Aa##s = *reinterpret_cast<const float4*>(p_); \
    Ab##s = *reinterpret_cast<const float4*>(p_ + 4); \
  } while (0)
#define MK(s) ({ short8v v_; \
    v_[0]=f2bf(Aa##s.x); v_[1]=f2bf(Aa##s.y); v_[2]=f2bf(Aa##s.z); v_[3]=f2bf(Aa##s.w); \
    v_[4]=f2bf(Ab##s.x); v_[5]=f2bf(Ab##s.y); v_[6]=f2bf(Ab##s.z); v_[7]=f2bf(Ab##s.w); v_; })
#define STEP(s, kcur) do { \
    short8v bf_ = *reinterpret_cast<const short8v*>(Xrow + (size_t)(kcur) * KT); \
    acc = __builtin_amdgcn_mfma_f32_16x16x32_bf16(MK(s), bf_, acc, 0, 0, 0); \
    LDA(s, (kcur) + DEPTH); \
  } while (0)

  float4 Aa0, Ab0, Aa1, Ab1, Aa2, Ab2, Aa3, Ab3;
  float4 Aa4, Ab4, Aa5, Ab5, Aa6, Ab6, Aa7, Ab7;
  LDA(0, 0); LDA(1, 1); LDA(2, 2); LDA(3, 3);
  LDA(4, 4); LDA(5, 5); LDA(6, 6); LDA(7, 7);

  for (int kb = 0; kb < njt3; kb += DEPTH) {       // njt3 % 8 == 0: no tail
    STEP(0, kb + 0); STEP(1, kb + 1); STEP(2, kb + 2); STEP(3, kb + 3);
    STEP(4, kb + 4); STEP(5, kb + 5); STEP(6, kb + 6); STEP(7, kb + 7);
  }
#undef LDA
#undef MK
#undef STEP

  // D frag: col = lane&15, row = (lane>>4)*4 + reg  [HW-validated rounds 4-5]
  const int orow = r0 + (wv << 4) + ((lane >> 4) << 2);
  #pragma unroll
  for (int r = 0; r < 4; ++r) {
    const int gr = orow + r;
    if (gr < cnt)
      out[(size_t)(sb + gr) * C + bcol] = acc[r];
  }
}

extern "C" void kernel_launch(void* const* d_in, const int* in_sizes, int n_in,
                              void* d_out, int out_size, void* d_ws, size_t ws_size,
                              hipStream_t stream) {
  const float* x     = (const float*)d_in[0];
  const float* M     = (const float*)d_in[1];
  const int*   batch = (const int*)d_in[2];
  float*       out   = (float*)d_out;
  const int n_nodes  = in_sizes[2];            // N = 65536
  const int B        = in_sizes[1] / (L * L);  // 128
  int* starts = (int*)d_ws;                    // B+1 ints of scratch

  starts_kernel<<<(n_nodes + 255) / 256, 256, 0, stream>>>(batch, n_nodes, B, starts);
  mp_kernel<<<dim3((L / RT) * B), dim3(256), 0, stream>>>(x, M, starts, out);
}

// Round 7
// 44.913 us; speedup vs baseline: 3.0025x; 1.0968x over previous
//
#include <hip/hip_runtime.h>
#include <hip/hip_bf16.h>

#define L 1024
#define C 16
#define RT 64            // output rows per block (4 waves x one 16x16 tile)
#define KT 32            // K per MFMA step
#define XSTR 1032        // shorts per Xt row

typedef __attribute__((ext_vector_type(8))) short short8v;  // bf16x8 frag
typedef __attribute__((ext_vector_type(4))) float f32x4;    // fp32 acc frag

static __device__ __forceinline__ short f2bf(float f) {
  __hip_bfloat16 h = __float2bfloat16(f);
  return __builtin_bit_cast(short, h);
}
static __device__ __forceinline__ int imin(int a, int b) { return a < b ? a : b; }

// Parallel boundary scan over sorted batch.
__global__ void starts_kernel(const int* __restrict__ batch, int n, int nb,
                              int* __restrict__ starts) {
  int i = blockIdx.x * blockDim.x + threadIdx.x;
  if (i >= n) return;
  int cur  = batch[i];
  int prev = (i == 0) ? -1 : batch[i - 1];
  for (int g = prev + 1; g <= cur; ++g) starts[g] = i;
  if (i == n - 1)
    for (int g = cur + 1; g <= nb; ++g) starts[g] = n;
}

__global__ __launch_bounds__(256, 4) void mp_kernel(
    const float* __restrict__ x,
    const float* __restrict__ M,
    const int*   __restrict__ starts,
    float*       __restrict__ out)
{
  __shared__ short Xt[C * XSTR];   // whole-graph x, transposed [ch][k], 33 KB

  // XCD swizzle: all row-tiles of graph b land on one XCD -> x hits that L2.
  const int gid = blockIdx.x;                      // 0..2047
  const int bx  = (gid >> 3) & 15;                 // row-tile 0..15
  const int b   = (gid & 7) | ((gid >> 7) << 3);   // graph 0..127 (bijective)

  const int sb = starts[b];
  int cnt = starts[b + 1] - sb;
  if (cnt > L) cnt = L;
  const int r0 = bx * RT;
  if (r0 >= cnt) return;                           // uniform

  const int njt   = (cnt + KT - 1) / KT;           // 1..32 real k-steps
  const int njtm1 = njt - 1;
  const int ng    = (njt + 3) >> 2;                // groups of 4 k-steps
  const int jmax4 = (ng << 2) * KT;                // zero-fill bound (<=1024)

  // ---- stage x transposed + bf16, zero-filled to jmax4 ----
  const float* xb = x + (size_t)sb * C;
  const int t = threadIdx.x;
  for (int j0 = t * 2; j0 < jmax4; j0 += 512) {
    const float4 fz = make_float4(0.f, 0.f, 0.f, 0.f);
    float4 va0 = fz, va1 = fz, vb0 = fz, vb1 = fz;
    float4 wa0 = fz, wa1 = fz, wb0 = fz, wb1 = fz;
    if (j0 < cnt) {
      va0 = *reinterpret_cast<const float4*>(xb + (size_t)j0 * C);
      va1 = *reinterpret_cast<const float4*>(xb + (size_t)j0 * C + 4);
      vb0 = *reinterpret_cast<const float4*>(xb + (size_t)j0 * C + 8);
      vb1 = *reinterpret_cast<const float4*>(xb + (size_t)j0 * C + 12);
    }
    if (j0 + 1 < cnt) {
      wa0 = *reinterpret_cast<const float4*>(xb + (size_t)(j0 + 1) * C);
      wa1 = *reinterpret_cast<const float4*>(xb + (size_t)(j0 + 1) * C + 4);
      wb0 = *reinterpret_cast<const float4*>(xb + (size_t)(j0 + 1) * C + 8);
      wb1 = *reinterpret_cast<const float4*>(xb + (size_t)(j0 + 1) * C + 12);
    }
    const float av[16] = {va0.x,va0.y,va0.z,va0.w, va1.x,va1.y,va1.z,va1.w,
                          vb0.x,vb0.y,vb0.z,vb0.w, vb1.x,vb1.y,vb1.z,vb1.w};
    const float bv[16] = {wa0.x,wa0.y,wa0.z,wa0.w, wa1.x,wa1.y,wa1.z,wa1.w,
                          wb0.x,wb0.y,wb0.z,wb0.w, wb1.x,wb1.y,wb1.z,wb1.w};
    #pragma unroll
    for (int c = 0; c < C; ++c) {
      short2 p; p.x = f2bf(av[c]); p.y = f2bf(bv[c]);
      *reinterpret_cast<short2*>(&Xt[c * XSTR + j0]) = p;
    }
  }
  asm volatile("s_waitcnt lgkmcnt(0)" ::: "memory");
  __builtin_amdgcn_s_barrier();

  // ---- MFMA roles: wave wv owns rows r0+wv*16..+15 ----
  const int lane = t & 63;
  const int wv   = t >> 6;
  const int arow = r0 + (wv << 4) + (lane & 15);
  const int kc8  = (lane >> 4) << 3;               // per-lane k chunk 0,8,16,24
  const int bcol = lane & 15;
  const float* Mrow = M + (size_t)b * (L * L) + (size_t)arow * L + kc8;
  const short* Xrow = &Xt[bcol * XSTR + kc8];

  f32x4 acc = {0.f, 0.f, 0.f, 0.f};

  // Group = 4 k-steps. 8 loads issued BACK-TO-BACK so each M row is visited
  // with 512 B contiguous per group (DRAM page locality), instead of 128 B
  // per k-step. Columns clamp to njtm1: padding steps re-read (L1 hit) and
  // their MFMA adds A*0 since Xt is zero there.
#define LDG(g, kbase) do { \
    const float* q0_ = Mrow + (size_t)imin((kbase) + 0, njtm1) * KT; \
    const float* q1_ = Mrow + (size_t)imin((kbase) + 1, njtm1) * KT; \
    const float* q2_ = Mrow + (size_t)imin((kbase) + 2, njtm1) * KT; \
    const float* q3_ = Mrow + (size_t)imin((kbase) + 3, njtm1) * KT; \
    A##g##0a = *reinterpret_cast<const float4*>(q0_); \
    A##g##0b = *reinterpret_cast<const float4*>(q0_ + 4); \
    A##g##1a = *reinterpret_cast<const float4*>(q1_); \
    A##g##1b = *reinterpret_cast<const float4*>(q1_ + 4); \
    A##g##2a = *reinterpret_cast<const float4*>(q2_); \
    A##g##2b = *reinterpret_cast<const float4*>(q2_ + 4); \
    A##g##3a = *reinterpret_cast<const float4*>(q3_); \
    A##g##3b = *reinterpret_cast<const float4*>(q3_ + 4); \
  } while (0)
#define MKF(a, bq) ({ short8v v_; \
    v_[0]=f2bf((a).x); v_[1]=f2bf((a).y); v_[2]=f2bf((a).z); v_[3]=f2bf((a).w); \
    v_[4]=f2bf((bq).x); v_[5]=f2bf((bq).y); v_[6]=f2bf((bq).z); v_[7]=f2bf((bq).w); v_; })
#define CONS(g, kbase) do { \
    short8v b0_ = *reinterpret_cast<const short8v*>(Xrow + (size_t)((kbase) + 0) * KT); \
    acc = __builtin_amdgcn_mfma_f32_16x16x32_bf16(MKF(A##g##0a, A##g##0b), b0_, acc, 0, 0, 0); \
    short8v b1_ = *reinterpret_cast<const short8v*>(Xrow + (size_t)((kbase) + 1) * KT); \
    acc = __builtin_amdgcn_mfma_f32_16x16x32_bf16(MKF(A##g##1a, A##g##1b), b1_, acc, 0, 0, 0); \
    short8v b2_ = *reinterpret_cast<const short8v*>(Xrow + (size_t)((kbase) + 2) * KT); \
    acc = __builtin_amdgcn_mfma_f32_16x16x32_bf16(MKF(A##g##2a, A##g##2b), b2_, acc, 0, 0, 0); \
    short8v b3_ = *reinterpret_cast<const short8v*>(Xrow + (size_t)((kbase) + 3) * KT); \
    acc = __builtin_amdgcn_mfma_f32_16x16x32_bf16(MKF(A##g##3a, A##g##3b), b3_, acc, 0, 0, 0); \
  } while (0)

  float4 A00a, A00b, A01a, A01b, A02a, A02b, A03a, A03b;   // group 0: 32 VGPR
  float4 A10a, A10b, A11a, A11b, A12a, A12b, A13a, A13b;   // group 1: 32 VGPR
  LDG(0, 0);
  LDG(1, 4);

  const int gpairs = ng >> 1;
  for (int gp = 0; gp < gpairs; ++gp) {
    const int kb = gp << 3;
    CONS(0, kb);     LDG(0, kb + 8);    // 2 groups (8 steps) stay in flight
    CONS(1, kb + 4); LDG(1, kb + 12);
  }
  if (ng & 1) CONS(0, gpairs << 3);     // odd group count: consume last group
#undef LDG
#undef MKF
#undef CONS

  // D frag: col = lane&15, row = (lane>>4)*4 + reg  [HW-validated rounds 4-6]
  const int orow = r0 + (wv << 4) + ((lane >> 4) << 2);
  #pragma unroll
  for (int r = 0; r < 4; ++r) {
    const int gr = orow + r;
    if (gr < cnt)
      out[(size_t)(sb + gr) * C + bcol] = acc[r];
  }
}

extern "C" void kernel_launch(void* const* d_in, const int* in_sizes, int n_in,
                              void* d_out, int out_size, void* d_ws, size_t ws_size,
                              hipStream_t stream) {
  const float* x     = (const float*)d_in[0];
  const float* M     = (const float*)d_in[1];
  const int*   batch = (const int*)d_in[2];
  float*       out   = (float*)d_out;
  const int n_nodes  = in_sizes[2];            // N = 65536
  const int B        = in_sizes[1] / (L * L);  // 128
  int* starts = (int*)d_ws;                    // B+1 ints of scratch

  starts_kernel<<<(n_nodes + 255) / 256, 256, 0, stream>>>(batch, n_nodes, B, starts);
  mp_kernel<<<dim3((L / RT) * B), dim3(256), 0, stream>>>(x, M, starts, out);
}